// Round 3
// baseline (276.908 us; speedup 1.0000x reference)
//
#include <hip/hip_runtime.h>

// DIST loss: out = sum_i sqrt((px_i-tx_i)^2 + (py_i-ty_i)^2) / (N+1)
// N = 16,777,216 points, float32 [N,2]. Memory-bound streaming reduction.
// R2 post-mortem: perf invariant to occupancy at ~2.7 TB/s effective ->
// access-pattern throughput wall, not latency. Fix: contiguous per-block
// tiles (DRAM page/burst locality) + compiler-barrier-forced 16-deep load
// batch (compiler was pairing load->use, VGPR_Count=20).

#define NBLOCKS 4096
#define NTHREADS 256
#define UNROLL 8   // float4s per thread; NBLOCKS*NTHREADS*UNROLL = 8,388,608 = n4

__global__ __launch_bounds__(NTHREADS, 2)
void dist_partial_kernel(const float4* __restrict__ preds,
                         const float4* __restrict__ targets,
                         float* __restrict__ partials,
                         int n4) {
    // Block b owns a contiguous tile of UNROLL*NTHREADS float4s (32 KB/array).
    const int tile_base = blockIdx.x * (UNROLL * NTHREADS) + threadIdx.x;

    float acc = 0.0f;

    if (tile_base + (UNROLL - 1) * NTHREADS < n4) {
        float4 p[UNROLL], t[UNROLL];
        #pragma unroll
        for (int k = 0; k < UNROLL; ++k) p[k] = preds[tile_base + k * NTHREADS];
        #pragma unroll
        for (int k = 0; k < UNROLL; ++k) t[k] = targets[tile_base + k * NTHREADS];
        // Force all 16 loads to issue before any compute (keep MLP deep).
        asm volatile("" ::: "memory");
        #pragma unroll
        for (int k = 0; k < UNROLL; ++k) {
            float dx0 = p[k].x - t[k].x;
            float dy0 = p[k].y - t[k].y;
            float dx1 = p[k].z - t[k].z;
            float dy1 = p[k].w - t[k].w;
            acc += sqrtf(dx0 * dx0 + dy0 * dy0);
            acc += sqrtf(dx1 * dx1 + dy1 * dy1);
        }
    } else {
        // Tail path (not taken for N=16M, kept for generality).
        for (int k = 0; k < UNROLL; ++k) {
            int i = tile_base + k * NTHREADS;
            if (i < n4) {
                float4 p = preds[i];
                float4 t = targets[i];
                float dx0 = p.x - t.x;
                float dy0 = p.y - t.y;
                float dx1 = p.z - t.z;
                float dy1 = p.w - t.w;
                acc += sqrtf(dx0 * dx0 + dy0 * dy0);
                acc += sqrtf(dx1 * dx1 + dy1 * dy1);
            }
        }
    }

    // wave-64 tree reduce
    #pragma unroll
    for (int off = 32; off > 0; off >>= 1)
        acc += __shfl_down(acc, off, 64);

    __shared__ float wave_sums[NTHREADS / 64];
    int lane = threadIdx.x & 63;
    int wave = threadIdx.x >> 6;
    if (lane == 0) wave_sums[wave] = acc;
    __syncthreads();

    if (threadIdx.x == 0) {
        float s = 0.0f;
        #pragma unroll
        for (int w = 0; w < NTHREADS / 64; ++w) s += wave_sums[w];
        partials[blockIdx.x] = s;
    }
}

__global__ __launch_bounds__(1024)
void dist_final_kernel(const float* __restrict__ partials,
                       float* __restrict__ out,
                       int nblocks, float inv_np1) {
    int tid = threadIdx.x;
    float acc = 0.0f;
    for (int i = tid; i < nblocks; i += 1024) acc += partials[i];

    #pragma unroll
    for (int off = 32; off > 0; off >>= 1)
        acc += __shfl_down(acc, off, 64);

    __shared__ float wave_sums[16];
    int lane = tid & 63;
    int wave = tid >> 6;
    if (lane == 0) wave_sums[wave] = acc;
    __syncthreads();

    if (tid == 0) {
        float s = 0.0f;
        #pragma unroll
        for (int w = 0; w < 16; ++w) s += wave_sums[w];
        out[0] = s * inv_np1;
    }
}

extern "C" void kernel_launch(void* const* d_in, const int* in_sizes, int n_in,
                              void* d_out, int out_size, void* d_ws, size_t ws_size,
                              hipStream_t stream) {
    const float4* preds   = (const float4*)d_in[0];
    const float4* targets = (const float4*)d_in[1];
    float* partials = (float*)d_ws;
    float* out = (float*)d_out;

    int n_elems  = in_sizes[0];      // N*2 floats = 33,554,432
    int n_points = n_elems / 2;      // 16,777,216
    int n4       = n_elems / 4;      // 8,388,608 float4s

    // Reference divides by float32(n+1); (float)(n_points+1) rounds to 2^24
    // identically to jnp.asarray(n+1, float32).
    float inv_np1 = 1.0f / (float)(n_points + 1);

    dist_partial_kernel<<<NBLOCKS, NTHREADS, 0, stream>>>(preds, targets, partials, n4);
    dist_final_kernel<<<1, 1024, 0, stream>>>(partials, out, NBLOCKS, inv_np1);
}

// Round 5
// 249.632 us; speedup vs baseline: 1.1093x; 1.1093x over previous
//
#include <hip/hip_runtime.h>

// DIST loss: out = sum_i sqrt((px_i-tx_i)^2 + (py_i-ty_i)^2) / (N+1)
// N = 16,777,216 points, float32 [N,2]. Streaming reduction, 268 MB read.
// R1-R3: ~100 us regardless of occupancy/pattern -> ~2.7 TB/s wall.
// FETCH_SIZE pinned at 50% of the 256 MiB working set (== L3 capacity):
// theory = our allocating reads thrash the restore-resident L3 copy.
// R5 change: nontemporal (no-allocate) loads via native clang vector type
// (R4 failed: builtin rejects HIP_vector_type).

typedef float floatx4 __attribute__((ext_vector_type(4)));

#define NBLOCKS 4096
#define NTHREADS 256
#define UNROLL 8   // float4s per thread; NBLOCKS*NTHREADS*UNROLL = 8,388,608 = n4

__global__ __launch_bounds__(NTHREADS, 2)
void dist_partial_kernel(const floatx4* __restrict__ preds,
                         const floatx4* __restrict__ targets,
                         float* __restrict__ partials,
                         int n4) {
    // Block b owns a contiguous tile of UNROLL*NTHREADS float4s (32 KB/array).
    const int tile_base = blockIdx.x * (UNROLL * NTHREADS) + threadIdx.x;

    float acc = 0.0f;

    if (tile_base + (UNROLL - 1) * NTHREADS < n4) {
        floatx4 p[UNROLL], t[UNROLL];
        #pragma unroll
        for (int k = 0; k < UNROLL; ++k)
            p[k] = __builtin_nontemporal_load(&preds[tile_base + k * NTHREADS]);
        #pragma unroll
        for (int k = 0; k < UNROLL; ++k)
            t[k] = __builtin_nontemporal_load(&targets[tile_base + k * NTHREADS]);
        asm volatile("" ::: "memory");
        #pragma unroll
        for (int k = 0; k < UNROLL; ++k) {
            float dx0 = p[k].x - t[k].x;
            float dy0 = p[k].y - t[k].y;
            float dx1 = p[k].z - t[k].z;
            float dy1 = p[k].w - t[k].w;
            acc += sqrtf(dx0 * dx0 + dy0 * dy0);
            acc += sqrtf(dx1 * dx1 + dy1 * dy1);
        }
    } else {
        // Tail path (not taken for N=16M, kept for generality).
        for (int k = 0; k < UNROLL; ++k) {
            int i = tile_base + k * NTHREADS;
            if (i < n4) {
                floatx4 p = preds[i];
                floatx4 t = targets[i];
                float dx0 = p.x - t.x;
                float dy0 = p.y - t.y;
                float dx1 = p.z - t.z;
                float dy1 = p.w - t.w;
                acc += sqrtf(dx0 * dx0 + dy0 * dy0);
                acc += sqrtf(dx1 * dx1 + dy1 * dy1);
            }
        }
    }

    // wave-64 tree reduce
    #pragma unroll
    for (int off = 32; off > 0; off >>= 1)
        acc += __shfl_down(acc, off, 64);

    __shared__ float wave_sums[NTHREADS / 64];
    int lane = threadIdx.x & 63;
    int wave = threadIdx.x >> 6;
    if (lane == 0) wave_sums[wave] = acc;
    __syncthreads();

    if (threadIdx.x == 0) {
        float s = 0.0f;
        #pragma unroll
        for (int w = 0; w < NTHREADS / 64; ++w) s += wave_sums[w];
        partials[blockIdx.x] = s;
    }
}

__global__ __launch_bounds__(1024)
void dist_final_kernel(const float* __restrict__ partials,
                       float* __restrict__ out,
                       int nblocks, float inv_np1) {
    int tid = threadIdx.x;
    float acc = 0.0f;
    for (int i = tid; i < nblocks; i += 1024) acc += partials[i];

    #pragma unroll
    for (int off = 32; off > 0; off >>= 1)
        acc += __shfl_down(acc, off, 64);

    __shared__ float wave_sums[16];
    int lane = tid & 63;
    int wave = tid >> 6;
    if (lane == 0) wave_sums[wave] = acc;
    __syncthreads();

    if (tid == 0) {
        float s = 0.0f;
        #pragma unroll
        for (int w = 0; w < 16; ++w) s += wave_sums[w];
        out[0] = s * inv_np1;
    }
}

extern "C" void kernel_launch(void* const* d_in, const int* in_sizes, int n_in,
                              void* d_out, int out_size, void* d_ws, size_t ws_size,
                              hipStream_t stream) {
    const floatx4* preds   = (const floatx4*)d_in[0];
    const floatx4* targets = (const floatx4*)d_in[1];
    float* partials = (float*)d_ws;
    float* out = (float*)d_out;

    int n_elems  = in_sizes[0];      // N*2 floats = 33,554,432
    int n_points = n_elems / 2;      // 16,777,216
    int n4       = n_elems / 4;      // 8,388,608 float4s

    // Reference divides by float32(n+1); (float)(n_points+1) rounds to 2^24
    // identically to jnp.asarray(n+1, float32).
    float inv_np1 = 1.0f / (float)(n_points + 1);

    dist_partial_kernel<<<NBLOCKS, NTHREADS, 0, stream>>>(preds, targets, partials, n4);
    dist_final_kernel<<<1, 1024, 0, stream>>>(partials, out, NBLOCKS, inv_np1);
}